// Round 24
// baseline (1692.670 us; speedup 1.0000x reference)
//
#include <hip/hip_runtime.h>
#include <hip/hip_bf16.h>

// Shapes: B=8, L=S=1024, D=1024, H=16, E=64, TOP_K=8.
// d_out = [ out (B*L*D f32) | A (B*H*L*S f32) ]
//
// PASSING reference model (R16, keep bit-exact):
//  - projections: ascending-k f32 FMA chain within K-panels {512,512}
//    (BLIS fixed KC=512), panels combined by single f32 adds; +bias, relu.
//  - scores: ONE ascending-e f32 FMA chain per score (K=64 single panel).
//  - top-8: thresh = 8th largest (multiplicity-counted); kept = s >= thresh.
//
// R24: fused score kernel rebuilt BARRIER-FREE and LDS-FREE: each wave
// independently owns 8 rows; K columns streamed directly from L2-resident
// Kt with coalesced float4 loads (lane u -> Kt[e][4u], 1KB/instr), loads
// pipelined by the compiler via vmcnt (no barriers to drain). acc[8][16]
// in registers under __launch_bounds__(256,2). Chain still ascending-e
// fmaf -> bit-exact. GEMM/transpose/vagg unchanged from R23.

#define B_ 8
#define L_ 1024
#define S_ 1024
#define D_ 1024
#define H_ 16
#define E_ 64
#define TOPK_ 8

// float -> orderable uint (monotone bijection)
__device__ __forceinline__ unsigned enc_ord(float f) {
  int s = __float_as_int(f);
  return (unsigned)(s ^ ((s >> 31) | 0x80000000));
}
__device__ __forceinline__ float dec_ord(unsigned u) {
  int m = ((int)u >= 0) ? 0xFFFFFFFF : 0x80000000;
  return __int_as_float((int)(u ^ (unsigned)m));
}

// wave64 max of ordered uints via DPP (row_shr + row_bcast), result uniform.
__device__ __forceinline__ unsigned dpp_umax64(unsigned x) {
  unsigned t;
  t = (unsigned)__builtin_amdgcn_update_dpp((int)x, (int)x, 0x111, 0xf, 0xf, false);
  x = x > t ? x : t;
  t = (unsigned)__builtin_amdgcn_update_dpp((int)x, (int)x, 0x112, 0xf, 0xf, false);
  x = x > t ? x : t;
  t = (unsigned)__builtin_amdgcn_update_dpp((int)x, (int)x, 0x114, 0xf, 0xf, false);
  x = x > t ? x : t;
  t = (unsigned)__builtin_amdgcn_update_dpp((int)x, (int)x, 0x118, 0xf, 0xf, false);
  x = x > t ? x : t;
  t = (unsigned)__builtin_amdgcn_update_dpp((int)x, (int)x, 0x142, 0xa, 0xf, false);
  x = x > t ? x : t;
  t = (unsigned)__builtin_amdgcn_update_dpp((int)x, (int)x, 0x143, 0xc, 0xf, false);
  x = x > t ? x : t;
  return (unsigned)__builtin_amdgcn_readlane((int)x, 63);
}

// wave64 float sum via DPP (identity 0), result uniform.
__device__ __forceinline__ float dpp_fsum64(float x) {
  float t;
  t = __int_as_float(__builtin_amdgcn_update_dpp(0, __float_as_int(x), 0x111, 0xf, 0xf, true));
  x += t;
  t = __int_as_float(__builtin_amdgcn_update_dpp(0, __float_as_int(x), 0x112, 0xf, 0xf, true));
  x += t;
  t = __int_as_float(__builtin_amdgcn_update_dpp(0, __float_as_int(x), 0x114, 0xf, 0xf, true));
  x += t;
  t = __int_as_float(__builtin_amdgcn_update_dpp(0, __float_as_int(x), 0x118, 0xf, 0xf, true));
  x += t;
  t = __int_as_float(__builtin_amdgcn_update_dpp(0, __float_as_int(x), 0x142, 0xa, 0xf, true));
  x += t;
  t = __int_as_float(__builtin_amdgcn_update_dpp(0, __float_as_int(x), 0x143, 0xc, 0xf, true));
  x += t;
  return __int_as_float(__builtin_amdgcn_readlane(__float_as_int(x), 63));
}

// ---------------------------------------------------------------------------
// C = A(MxK,row) * B(NxK,row)^T + bias, optional relu. f32; ascending-k FMA
// chain within BLIS panels {512,512} (flush after k-tiles 31, 63), f32 adds
// across panels. Single-barrier LDS double-buffer; dwordx4 staging.
// ---------------------------------------------------------------------------
template <int RELU>
__global__ __launch_bounds__(256) void gemm_abt(
    const float* __restrict__ A, const float* __restrict__ Bm,
    const float* __restrict__ bias, float* __restrict__ C,
    int M, int N, int K, int lda, int ldb, int ldc) {
  __shared__ float As[2][16][68];
  __shared__ float Bs[2][16][68];

  const int t = threadIdx.x;
  const int tx = t & 15, ty = t >> 4;
  const int m0 = blockIdx.y * 64, n0 = blockIdx.x * 64;
  const int sr = t >> 2, skq = (t & 3) * 4;

  float acc[4][4], tot[4][4];
#pragma unroll
  for (int r = 0; r < 4; ++r)
#pragma unroll
    for (int c = 0; c < 4; ++c) {
      acc[r][c] = 0.0f;
      tot[r][c] = 0.0f;
    }

  const float* Arow = A + (long long)(m0 + sr) * lda + skq;
  const float* Brow = Bm + (long long)(n0 + sr) * ldb + skq;

  float4 pa = *reinterpret_cast<const float4*>(Arow);
  float4 pb = *reinterpret_cast<const float4*>(Brow);
  {
    As[0][skq + 0][sr] = pa.x;
    As[0][skq + 1][sr] = pa.y;
    As[0][skq + 2][sr] = pa.z;
    As[0][skq + 3][sr] = pa.w;
    Bs[0][skq + 0][sr] = pb.x;
    Bs[0][skq + 1][sr] = pb.y;
    Bs[0][skq + 2][sr] = pb.z;
    Bs[0][skq + 3][sr] = pb.w;
  }
  __syncthreads();

  const int ntiles = K / 16;
  for (int ti = 0; ti < ntiles; ++ti) {
    const int cur = ti & 1, nxt = cur ^ 1;
    if (ti + 1 < ntiles) {
      pa = *reinterpret_cast<const float4*>(Arow + (ti + 1) * 16);
      pb = *reinterpret_cast<const float4*>(Brow + (ti + 1) * 16);
    }
#pragma unroll
    for (int kk = 0; kk < 16; ++kk) {
      const float4 a4 = *reinterpret_cast<const float4*>(&As[cur][kk][ty * 4]);
      const float4 b4 = *reinterpret_cast<const float4*>(&Bs[cur][kk][tx * 4]);
      const float av[4] = {a4.x, a4.y, a4.z, a4.w};
      const float bv[4] = {b4.x, b4.y, b4.z, b4.w};
#pragma unroll
      for (int r = 0; r < 4; ++r)
#pragma unroll
        for (int c = 0; c < 4; ++c) acc[r][c] = fmaf(av[r], bv[c], acc[r][c]);
    }
    if (ti + 1 < ntiles) {
      As[nxt][skq + 0][sr] = pa.x;
      As[nxt][skq + 1][sr] = pa.y;
      As[nxt][skq + 2][sr] = pa.z;
      As[nxt][skq + 3][sr] = pa.w;
      Bs[nxt][skq + 0][sr] = pb.x;
      Bs[nxt][skq + 1][sr] = pb.y;
      Bs[nxt][skq + 2][sr] = pb.z;
      Bs[nxt][skq + 3][sr] = pb.w;
    }
    const bool flush =
        (K == 1024) ? (ti == 31 || ti == 63) : (ti == ntiles - 1);
    if (flush) {
#pragma unroll
      for (int r = 0; r < 4; ++r)
#pragma unroll
        for (int c = 0; c < 4; ++c) {
          tot[r][c] = __fadd_rn(tot[r][c], acc[r][c]);
          acc[r][c] = 0.0f;
        }
    }
    __syncthreads();
  }

#pragma unroll
  for (int r = 0; r < 4; ++r) {
    const int m = m0 + ty * 4 + r;
#pragma unroll
    for (int c = 0; c < 4; ++c) {
      const int n = n0 + tx * 4 + c;
      float v = tot[r][c];
      if (bias) v = __fadd_rn(v, bias[n]);
      if (RELU) v = fmaxf(v, 0.0f);
      C[(long long)m * ldc + n] = v;
    }
  }
}

// ---------------------------------------------------------------------------
// Transpose K head-slices: Kt[(b*16+h)*64 + e][s] = Kf[(b*1024+s)][h*64+e].
// ---------------------------------------------------------------------------
__global__ __launch_bounds__(256) void transpose_k(const float* __restrict__ Kf,
                                                   float* __restrict__ Kt) {
  __shared__ float tl[64][65];
  const int bh = blockIdx.y;
  const int b = bh >> 4, h = bh & 15;
  const int s0 = blockIdx.x * 64;
  const int t = threadIdx.x;
#pragma unroll
  for (int i = 0; i < 16; ++i) {
    const int idx = i * 256 + t;
    const int sr = idx >> 6, e = idx & 63;
    tl[sr][e] = Kf[(((long long)(b << 10) + s0 + sr) << 10) + (h << 6) + e];
  }
  __syncthreads();
#pragma unroll
  for (int i = 0; i < 16; ++i) {
    const int idx = i * 256 + t;
    const int er = idx >> 6, s = idx & 63;
    Kt[(((long long)(bh << 6) + er) << 10) + s0 + s] = tl[s][er];
  }
}

// ---------------------------------------------------------------------------
// Fused scores + top-8 + softmax. NO LDS, NO BARRIERS: each wave owns 8
// rows; K streamed from L2-resident Kt via coalesced float4 loads, pipelined
// by vmcnt. acc[8][16] registers under launch_bounds(256,2) (no spill).
// Per score: e ascends 0..63, fmaf -> bit-exact. Epilogue: ownerless
// descending-threshold top-8 (ties exact), DPP reduces, 8 rows interleaved.
// ---------------------------------------------------------------------------
__global__ __launch_bounds__(256, 2) void score_topk_fused(
    const float* __restrict__ Qf, const float* __restrict__ Kt,
    float* __restrict__ A, int* __restrict__ outIdx,
    float* __restrict__ outW, int* __restrict__ outCnt) {
#pragma clang fp contract(off)
  const int t = threadIdx.x;
  const int wv = t >> 6, u = t & 63;
  const long long row0 = (long long)blockIdx.x * 32 + wv * 8;
  const int b = (int)(row0 >> 14), h = (int)((row0 >> 10) & 15);
  const int bh = (b << 4) + h;
  const int l0 = (int)(row0 & 1023);

  float qreg[8];
#pragma unroll
  for (int r = 0; r < 8; ++r)
    qreg[r] = Qf[(((long long)(b << 10) + l0 + r) << 10) + (h << 6) + u];

  const float* KtBase = Kt + ((long long)(bh << 6) << 10);  // [64][1024]

  float acc[8][16];
#pragma unroll
  for (int r = 0; r < 8; ++r)
#pragma unroll
    for (int j = 0; j < 16; ++j) acc[r][j] = 0.0f;

#pragma unroll
  for (int sweep = 0; sweep < 4; ++sweep) {
    const float* Kcol = KtBase + sweep * 256 + 4 * u;
#pragma unroll 8
    for (int e = 0; e < 64; ++e) {
      const float4 k4 =
          *reinterpret_cast<const float4*>(Kcol + ((long long)e << 10));
#pragma unroll
      for (int r = 0; r < 8; ++r) {
        const float qv = __uint_as_float(
            __builtin_amdgcn_readlane(__float_as_uint(qreg[r]), e));
        acc[r][sweep * 4 + 0] = fmaf(qv, k4.x, acc[r][sweep * 4 + 0]);
        acc[r][sweep * 4 + 1] = fmaf(qv, k4.y, acc[r][sweep * 4 + 1]);
        acc[r][sweep * 4 + 2] = fmaf(qv, k4.z, acc[r][sweep * 4 + 2]);
        acc[r][sweep * 4 + 3] = fmaf(qv, k4.w, acc[r][sweep * 4 + 3]);
      }
    }
  }
  // acc[r][sweep*4+c] = col sweep*256 + 4u + c

  // ---- top-8 thresholds, 8 rows interleaved, descending extraction ----
  float T[8], cnt8[8], rowmax[8];
#pragma unroll
  for (int r = 0; r < 8; ++r) {
    T[r] = INFINITY;
    cnt8[r] = 0.0f;
    rowmax[r] = 0.0f;
  }

  for (int it = 0; it < TOPK_; ++it) {
    float m[8];
#pragma unroll
    for (int r = 0; r < 8; ++r) {
      float lm = -INFINITY;
#pragma unroll
      for (int j = 0; j < 16; ++j) {
        const float v = acc[r][j];
        lm = fmaxf(lm, v < T[r] ? v : -INFINITY);
      }
      m[r] = lm;
    }
    unsigned mu[8];
#pragma unroll
    for (int r = 0; r < 8; ++r) mu[r] = enc_ord(m[r]);
#pragma unroll
    for (int r = 0; r < 8; ++r) mu[r] = dpp_umax64(mu[r]);
#pragma unroll
    for (int r = 0; r < 8; ++r) m[r] = dec_ord(mu[r]);

    float nn[8];
#pragma unroll
    for (int r = 0; r < 8; ++r) {
      float cl = 0.0f;
#pragma unroll
      for (int j = 0; j < 16; ++j) cl += (acc[r][j] == m[r]) ? 1.0f : 0.0f;
      nn[r] = cl;
    }
#pragma unroll
    for (int r = 0; r < 8; ++r) nn[r] = dpp_fsum64(nn[r]);

#pragma unroll
    for (int r = 0; r < 8; ++r) {
      if (it == 0) rowmax[r] = m[r];
      const bool upd = (cnt8[r] < 8.0f);
      T[r] = upd ? m[r] : T[r];
      cnt8[r] = upd ? cnt8[r] + nn[r] : cnt8[r];
    }
  }

  // ---- softmax + masked write + compact lists (per row) ----
#pragma unroll
  for (int r = 0; r < 8; ++r) {
    const float thresh = T[r];
    float e16[16];
    float zl = 0.0f;
#pragma unroll
    for (int j = 0; j < 16; ++j) {
      const bool kept = (acc[r][j] >= thresh);
      const float e = kept ? __expf((acc[r][j] - rowmax[r]) * 0.125f) : 0.0f;
      e16[j] = e;
      zl += e;
    }
    const float zsum = dpp_fsum64(zl);
    const float inv = 1.0f / zsum;

    const long long row = row0 + r;
    float* a = A + (row << 10);
    int cnt = 0;
#pragma unroll
    for (int j = 0; j < 16; ++j) {
      const bool kept = (acc[r][j] >= thresh);
      const float w = e16[j] * inv;
      e16[j] = kept ? w : 0.0f;
      const unsigned long long mk = __ballot(kept);
      if (kept) {
        const int pos = cnt + __popcll(mk & ((1ull << u) - 1ull));
        if (pos < 16) {
          const int col = (j >> 2) * 256 + 4 * u + (j & 3);
          outIdx[row * 16 + pos] = col;
          outW[row * 16 + pos] = w;
        }
      }
      cnt += __popcll(mk);
    }
    if (u == 0) outCnt[row] = cnt < 16 ? cnt : 16;

#pragma unroll
    for (int blkc = 0; blkc < 4; ++blkc) {
      float4 o;
      o.x = e16[blkc * 4 + 0];
      o.y = e16[blkc * 4 + 1];
      o.z = e16[blkc * 4 + 2];
      o.w = e16[blkc * 4 + 3];
      *reinterpret_cast<float4*>(&a[blkc * 256 + 4 * u]) = o;
    }
  }
}

// ---------------------------------------------------------------------------
// Sparse A*v from compact lists. One wave per row (lane = e).
// ---------------------------------------------------------------------------
__global__ __launch_bounds__(256) void vagg_kernel(
    const int* __restrict__ idx, const float* __restrict__ w,
    const int* __restrict__ cnt, const float* __restrict__ Vp,
    float* __restrict__ Vagg) {
  const int wave = threadIdx.x >> 6;
  const int lane = threadIdx.x & 63;
  const long long row = (long long)blockIdx.x * 4 + wave;
  const int b = (int)(row >> 14);
  const int h = (int)((row >> 10) & 15);
  const int l = (int)(row & 1023);
  const int n = cnt[row];
  float acc = 0.0f;
  for (int i = 0; i < n; ++i) {
    const int sI = idx[row * 16 + i];
    const float ww = w[row * 16 + i];
    acc += ww * Vp[((long long)((b << 10) + sI) << 10) + (h << 6) + lane];
  }
  Vagg[((long long)((b << 10) + l) << 10) + (h << 6) + lane] = acc;
}

extern "C" void kernel_launch(void* const* d_in, const int* in_sizes, int n_in,
                              void* d_out, int out_size, void* d_ws,
                              size_t ws_size, hipStream_t stream) {
  const float* queries = (const float*)d_in[0];
  const float* keys = (const float*)d_in[1];
  const float* values = (const float*)d_in[2];
  const float* Wq = (const float*)d_in[3];
  const float* bq = (const float*)d_in[4];
  const float* Wk = (const float*)d_in[5];
  const float* bk = (const float*)d_in[6];
  const float* Wv = (const float*)d_in[7];
  const float* bv = (const float*)d_in[8];
  const float* Wo = (const float*)d_in[9];
  const float* bo = (const float*)d_in[10];

  float* out = (float*)d_out;                   // [B,L,D]
  float* Aout = out + (long long)B_ * L_ * D_;  // [B,H,L,S]

  char* ws = (char*)d_ws;
  const size_t MD = (size_t)B_ * L_ * D_ * sizeof(float);  // 33.55 MB
  const size_t NL = (size_t)B_ * H_ * L_;                   // 131072 rows
  float* Qf = (float*)ws;
  float* Kf = (float*)(ws + MD);
  float* Kt = (float*)(ws + 2 * MD);
  int* tIdx = (int*)(ws + 3 * MD);
  float* tW = (float*)(ws + 3 * MD + NL * 16 * 4);
  int* tCnt = (int*)(ws + 3 * MD + NL * 16 * 8);
  float* Vb = (float*)(ws + 3 * MD + NL * 16 * 8 + NL * 4);
  float* Vagg = Kt;  // Kt dead after score_topk_fused

  const dim3 blk(256);
  const int M = B_ * L_;  // 8192

  // Q = relu(queries @ Wq^T + bq)   [bit-exact chain]
  gemm_abt<1><<<dim3(16, M / 64), blk, 0, stream>>>(queries, Wq, bq, Qf, M, D_,
                                                    D_, D_, D_, D_);
  // K = keys @ Wk^T + bk            [bit-exact chain]
  gemm_abt<0><<<dim3(16, M / 64), blk, 0, stream>>>(keys, Wk, bk, Kf, M, D_,
                                                    D_, D_, D_, D_);
  // Kt[b,h,e,s] = Kf[b,s,h,e]
  transpose_k<<<dim3(16, B_ * H_), blk, 0, stream>>>(Kf, Kt);

  // fused scores + top-8 + softmax -> A + compact lists (barrier-free)
  score_topk_fused<<<(int)(NL / 32), blk, 0, stream>>>(Qf, Kt, Aout, tIdx, tW,
                                                       tCnt);

  // V = relu(values @ Wv^T + bv)
  gemm_abt<1><<<dim3(16, M / 64), blk, 0, stream>>>(values, Wv, bv, Vb, M, D_,
                                                    D_, D_, D_, D_);

  // Vagg[b,l,h,:] = sum_s A * v   (writes into Kt slot)
  vagg_kernel<<<(int)(NL / 4), blk, 0, stream>>>(tIdx, tW, tCnt, Vb, Vagg);

  // out = Vagg @ Wo^T + bo
  gemm_abt<0><<<dim3(16, M / 64), blk, 0, stream>>>(Vagg, Wo, bo, out, M, D_,
                                                    D_, D_, D_, D_);
}

// Round 25
// 1212.819 us; speedup vs baseline: 1.3956x; 1.3956x over previous
//
#include <hip/hip_runtime.h>
#include <hip/hip_bf16.h>

// Shapes: B=8, L=S=1024, D=1024, H=16, E=64, TOP_K=8.
// d_out = [ out (B*L*D f32) | A (B*H*L*S f32) ]
//
// PASSING reference model (R16, keep bit-exact ON THE SELECTION PATH):
//  - Q/K projections: ascending-k f32 FMA chain within K-panels {512,512}
//    (BLIS KC=512), panels combined by single f32 adds; +bias, relu.
//  - scores: ONE ascending-e f32 FMA chain per score (K=64 single panel).
//  - top-8: thresh = 8th largest (multiplicity-counted); kept = s >= thresh.
// V-projection and out-GEMM are VALUE-LEVEL (2%*max tolerance, bf16-granular
// compare) -> R25 runs them on bf16 MFMA (f32 accumulate).
//
// R25: fused kernel reverted to R23's verified version (R24 spilled).
// V-proj + out-GEMM -> mfma_f32_16x16x32_bf16 (64x64 tile, 4 waves x4 MFMA,
// LDS [64][40] bf16, single-barrier double buffer).

#define B_ 8
#define L_ 1024
#define S_ 1024
#define D_ 1024
#define H_ 16
#define E_ 64
#define TOPK_ 8

typedef __attribute__((ext_vector_type(8))) short bfrag8;
typedef __attribute__((ext_vector_type(4))) float f4acc;

__device__ __forceinline__ void gload_lds16(const float* g, float* l) {
  __builtin_amdgcn_global_load_lds(
      (const __attribute__((address_space(1))) unsigned int*)g,
      (__attribute__((address_space(3))) unsigned int*)l, 16, 0, 0);
}

__device__ __forceinline__ unsigned short f2bf(float f) {
  unsigned u = __float_as_uint(f);
  u += 0x7FFF + ((u >> 16) & 1);  // round-to-nearest-even
  return (unsigned short)(u >> 16);
}

// float -> orderable uint (monotone bijection)
__device__ __forceinline__ unsigned enc_ord(float f) {
  int s = __float_as_int(f);
  return (unsigned)(s ^ ((s >> 31) | 0x80000000));
}
__device__ __forceinline__ float dec_ord(unsigned u) {
  int m = ((int)u >= 0) ? 0xFFFFFFFF : 0x80000000;
  return __int_as_float((int)(u ^ (unsigned)m));
}

// wave64 max of ordered uints via DPP, result uniform.
__device__ __forceinline__ unsigned dpp_umax64(unsigned x) {
  unsigned t;
  t = (unsigned)__builtin_amdgcn_update_dpp((int)x, (int)x, 0x111, 0xf, 0xf, false);
  x = x > t ? x : t;
  t = (unsigned)__builtin_amdgcn_update_dpp((int)x, (int)x, 0x112, 0xf, 0xf, false);
  x = x > t ? x : t;
  t = (unsigned)__builtin_amdgcn_update_dpp((int)x, (int)x, 0x114, 0xf, 0xf, false);
  x = x > t ? x : t;
  t = (unsigned)__builtin_amdgcn_update_dpp((int)x, (int)x, 0x118, 0xf, 0xf, false);
  x = x > t ? x : t;
  t = (unsigned)__builtin_amdgcn_update_dpp((int)x, (int)x, 0x142, 0xa, 0xf, false);
  x = x > t ? x : t;
  t = (unsigned)__builtin_amdgcn_update_dpp((int)x, (int)x, 0x143, 0xc, 0xf, false);
  x = x > t ? x : t;
  return (unsigned)__builtin_amdgcn_readlane((int)x, 63);
}

// wave64 float sum via DPP (identity 0), result uniform.
__device__ __forceinline__ float dpp_fsum64(float x) {
  float t;
  t = __int_as_float(__builtin_amdgcn_update_dpp(0, __float_as_int(x), 0x111, 0xf, 0xf, true));
  x += t;
  t = __int_as_float(__builtin_amdgcn_update_dpp(0, __float_as_int(x), 0x112, 0xf, 0xf, true));
  x += t;
  t = __int_as_float(__builtin_amdgcn_update_dpp(0, __float_as_int(x), 0x114, 0xf, 0xf, true));
  x += t;
  t = __int_as_float(__builtin_amdgcn_update_dpp(0, __float_as_int(x), 0x118, 0xf, 0xf, true));
  x += t;
  t = __int_as_float(__builtin_amdgcn_update_dpp(0, __float_as_int(x), 0x142, 0xa, 0xf, true));
  x += t;
  t = __int_as_float(__builtin_amdgcn_update_dpp(0, __float_as_int(x), 0x143, 0xc, 0xf, true));
  x += t;
  return __int_as_float(__builtin_amdgcn_readlane(__float_as_int(x), 63));
}

// ---------------------------------------------------------------------------
// BIT-EXACT f32 GEMM (Q/K projections): C = A*B^T + bias, optional relu;
// ascending-k FMA chain within BLIS panels {512,512}, f32 adds across
// panels. Single-barrier LDS double-buffer (R23, verified).
// ---------------------------------------------------------------------------
template <int RELU>
__global__ __launch_bounds__(256) void gemm_abt(
    const float* __restrict__ A, const float* __restrict__ Bm,
    const float* __restrict__ bias, float* __restrict__ C,
    int M, int N, int K, int lda, int ldb, int ldc) {
  __shared__ float As[2][16][68];
  __shared__ float Bs[2][16][68];

  const int t = threadIdx.x;
  const int tx = t & 15, ty = t >> 4;
  const int m0 = blockIdx.y * 64, n0 = blockIdx.x * 64;
  const int sr = t >> 2, skq = (t & 3) * 4;

  float acc[4][4], tot[4][4];
#pragma unroll
  for (int r = 0; r < 4; ++r)
#pragma unroll
    for (int c = 0; c < 4; ++c) {
      acc[r][c] = 0.0f;
      tot[r][c] = 0.0f;
    }

  const float* Arow = A + (long long)(m0 + sr) * lda + skq;
  const float* Brow = Bm + (long long)(n0 + sr) * ldb + skq;

  float4 pa = *reinterpret_cast<const float4*>(Arow);
  float4 pb = *reinterpret_cast<const float4*>(Brow);
  {
    As[0][skq + 0][sr] = pa.x;
    As[0][skq + 1][sr] = pa.y;
    As[0][skq + 2][sr] = pa.z;
    As[0][skq + 3][sr] = pa.w;
    Bs[0][skq + 0][sr] = pb.x;
    Bs[0][skq + 1][sr] = pb.y;
    Bs[0][skq + 2][sr] = pb.z;
    Bs[0][skq + 3][sr] = pb.w;
  }
  __syncthreads();

  const int ntiles = K / 16;
  for (int ti = 0; ti < ntiles; ++ti) {
    const int cur = ti & 1, nxt = cur ^ 1;
    if (ti + 1 < ntiles) {
      pa = *reinterpret_cast<const float4*>(Arow + (ti + 1) * 16);
      pb = *reinterpret_cast<const float4*>(Brow + (ti + 1) * 16);
    }
#pragma unroll
    for (int kk = 0; kk < 16; ++kk) {
      const float4 a4 = *reinterpret_cast<const float4*>(&As[cur][kk][ty * 4]);
      const float4 b4 = *reinterpret_cast<const float4*>(&Bs[cur][kk][tx * 4]);
      const float av[4] = {a4.x, a4.y, a4.z, a4.w};
      const float bv[4] = {b4.x, b4.y, b4.z, b4.w};
#pragma unroll
      for (int r = 0; r < 4; ++r)
#pragma unroll
        for (int c = 0; c < 4; ++c) acc[r][c] = fmaf(av[r], bv[c], acc[r][c]);
    }
    if (ti + 1 < ntiles) {
      As[nxt][skq + 0][sr] = pa.x;
      As[nxt][skq + 1][sr] = pa.y;
      As[nxt][skq + 2][sr] = pa.z;
      As[nxt][skq + 3][sr] = pa.w;
      Bs[nxt][skq + 0][sr] = pb.x;
      Bs[nxt][skq + 1][sr] = pb.y;
      Bs[nxt][skq + 2][sr] = pb.z;
      Bs[nxt][skq + 3][sr] = pb.w;
    }
    const bool flush =
        (K == 1024) ? (ti == 31 || ti == 63) : (ti == ntiles - 1);
    if (flush) {
#pragma unroll
      for (int r = 0; r < 4; ++r)
#pragma unroll
        for (int c = 0; c < 4; ++c) {
          tot[r][c] = __fadd_rn(tot[r][c], acc[r][c]);
          acc[r][c] = 0.0f;
        }
    }
    __syncthreads();
  }

#pragma unroll
  for (int r = 0; r < 4; ++r) {
    const int m = m0 + ty * 4 + r;
#pragma unroll
    for (int c = 0; c < 4; ++c) {
      const int n = n0 + tx * 4 + c;
      float v = tot[r][c];
      if (bias) v = __fadd_rn(v, bias[n]);
      if (RELU) v = fmaxf(v, 0.0f);
      C[(long long)m * ldc + n] = v;
    }
  }
}

// ---------------------------------------------------------------------------
// VALUE-LEVEL bf16-MFMA GEMM (V-proj, out-GEMM): C = A*B^T + bias, relu opt.
// Inputs RNE-rounded to bf16; f32 accumulate via mfma_f32_16x16x32_bf16.
// 64x64 tile, 4 waves; wave w owns rows [16w,16w+16), 4 n-tiles.
// A/B frag: lane l = idx + 16*g holds k = g*8+j. C/D: col=l&15,
// row=(l>>4)*4+reg (m89-verified). LDS [64][40] bf16 (16B-aligned rows,
// ~2-way banks), single-barrier double buffer.
// ---------------------------------------------------------------------------
template <int RELU>
__global__ __launch_bounds__(256) void gemm_mfma(
    const float* __restrict__ A, const float* __restrict__ Bm,
    const float* __restrict__ bias, float* __restrict__ C,
    int M, int N, int K, int lda, int ldb, int ldc) {
  __shared__ unsigned short As[2][64][40];
  __shared__ unsigned short Bs[2][64][40];

  const int t = threadIdx.x;
  const int w = t >> 6, l = t & 63;
  const int lr = l & 15, lg = l >> 4;
  const int m0 = blockIdx.y * 64, n0 = blockIdx.x * 64;
  const int srow = t >> 2, scol = (t & 3) * 8;  // staging: 8 f32/thread

  f4acc acc[4];
#pragma unroll
  for (int c = 0; c < 4; ++c) acc[c] = (f4acc){0.f, 0.f, 0.f, 0.f};

  const float* Arow = A + (long long)(m0 + srow) * lda + scol;
  const float* Brow = Bm + (long long)(n0 + srow) * ldb + scol;

  float4 pa0 = *reinterpret_cast<const float4*>(Arow);
  float4 pa1 = *reinterpret_cast<const float4*>(Arow + 4);
  float4 pb0 = *reinterpret_cast<const float4*>(Brow);
  float4 pb1 = *reinterpret_cast<const float4*>(Brow + 4);

  auto store_tile = [&](int buf, const float4& a0, const float4& a1,
                        const float4& b0, const float4& b1) {
    unsigned short* ap = &As[buf][srow][scol];
    ap[0] = f2bf(a0.x); ap[1] = f2bf(a0.y); ap[2] = f2bf(a0.z);
    ap[3] = f2bf(a0.w); ap[4] = f2bf(a1.x); ap[5] = f2bf(a1.y);
    ap[6] = f2bf(a1.z); ap[7] = f2bf(a1.w);
    unsigned short* bp = &Bs[buf][srow][scol];
    bp[0] = f2bf(b0.x); bp[1] = f2bf(b0.y); bp[2] = f2bf(b0.z);
    bp[3] = f2bf(b0.w); bp[4] = f2bf(b1.x); bp[5] = f2bf(b1.y);
    bp[6] = f2bf(b1.z); bp[7] = f2bf(b1.w);
  };

  store_tile(0, pa0, pa1, pb0, pb1);
  __syncthreads();

  const int nsteps = K / 32;
  for (int ks = 0; ks < nsteps; ++ks) {
    const int cur = ks & 1, nxt = cur ^ 1;
    if (ks + 1 < nsteps) {
      const int off = (ks + 1) * 32;
      pa0 = *reinterpret_cast<const float4*>(Arow + off);
      pa1 = *reinterpret_cast<const float4*>(Arow + off + 4);
      pb0 = *reinterpret_cast<const float4*>(Brow + off);
      pb1 = *reinterpret_cast<const float4*>(Brow + off + 4);
    }
    const bfrag8 av =
        *reinterpret_cast<const bfrag8*>(&As[cur][16 * w + lr][lg * 8]);
#pragma unroll
    for (int c = 0; c < 4; ++c) {
      const bfrag8 bv =
          *reinterpret_cast<const bfrag8*>(&Bs[cur][16 * c + lr][lg * 8]);
      acc[c] = __builtin_amdgcn_mfma_f32_16x16x32_bf16(av, bv, acc[c], 0, 0, 0);
    }
    if (ks + 1 < nsteps) store_tile(nxt, pa0, pa1, pb0, pb1);
    __syncthreads();
  }

#pragma unroll
  for (int c = 0; c < 4; ++c) {
    const int col = n0 + c * 16 + lr;
    const float bb = bias ? bias[col] : 0.0f;
#pragma unroll
    for (int j = 0; j < 4; ++j) {
      const int row = m0 + 16 * w + lg * 4 + j;
      float v = acc[c][j] + bb;
      if (RELU) v = fmaxf(v, 0.0f);
      C[(long long)row * ldc + col] = v;
    }
  }
}

// ---------------------------------------------------------------------------
// Transpose K head-slices: Kt[(b*16+h)*64 + e][s] = Kf[(b*1024+s)][h*64+e].
// ---------------------------------------------------------------------------
__global__ __launch_bounds__(256) void transpose_k(const float* __restrict__ Kf,
                                                   float* __restrict__ Kt) {
  __shared__ float tl[64][65];
  const int bh = blockIdx.y;
  const int b = bh >> 4, h = bh & 15;
  const int s0 = blockIdx.x * 64;
  const int t = threadIdx.x;
#pragma unroll
  for (int i = 0; i < 16; ++i) {
    const int idx = i * 256 + t;
    const int sr = idx >> 6, e = idx & 63;
    tl[sr][e] = Kf[(((long long)(b << 10) + s0 + sr) << 10) + (h << 6) + e];
  }
  __syncthreads();
#pragma unroll
  for (int i = 0; i < 16; ++i) {
    const int idx = i * 256 + t;
    const int er = idx >> 6, s = idx & 63;
    Kt[(((long long)(bh << 6) + er) << 10) + s0 + s] = tl[s][er];
  }
}

// ---------------------------------------------------------------------------
// Fused scores + top-8 + softmax (R22/R23 version, verified @530us).
// ---------------------------------------------------------------------------
__global__ __launch_bounds__(256, 4) void score_topk_fused(
    const float* __restrict__ Qf, const float* __restrict__ Kt,
    float* __restrict__ A, int* __restrict__ outIdx,
    float* __restrict__ outW, int* __restrict__ outCnt) {
#pragma clang fp contract(off)
  __shared__ float Ks[2][8][512];

  const int t = threadIdx.x;
  const int wv = t >> 6, u = t & 63;
  const int row0 = blockIdx.x * 16;
  const int b = row0 >> 14, h = (row0 >> 10) & 15;
  const int bh = (b << 4) + h;
  const int rbase = (row0 & 1023) + wv * 4;

  float qreg[4];
#pragma unroll
  for (int r = 0; r < 4; ++r)
    qreg[r] = Qf[(((long long)(b << 10) + rbase + r) << 10) + (h << 6) + u];

  const float* KtBase = Kt + ((long long)(bh << 6) << 10);  // [64][1024]

  float acc[4][16];
#pragma unroll
  for (int r = 0; r < 4; ++r)
#pragma unroll
    for (int j = 0; j < 16; ++j) acc[r][j] = 0.0f;

  auto stage = [&](int buf, int eo, int ch) {
    const int r0 = wv * 2;
#pragma unroll
    for (int i = 0; i < 2; ++i) {
      const float* src =
          KtBase + ((long long)(eo * 8 + r0 + i) << 10) + ch * 512;
      float* dst = &Ks[buf][r0 + i][0];
      gload_lds16(src + 4 * u, dst);
      gload_lds16(src + 256 + 4 * u, dst + 256);
    }
  };

  stage(0, 0, 0);
  __syncthreads();

  for (int eo = 0; eo < 8; ++eo) {
    float qv[8][4];
#pragma unroll
    for (int el = 0; el < 8; ++el)
#pragma unroll
      for (int r = 0; r < 4; ++r)
        qv[el][r] = __uint_as_float(__builtin_amdgcn_readlane(
            __float_as_uint(qreg[r]), eo * 8 + el));

    {  // ch = 0
      stage(1, eo, 1);
#pragma unroll
      for (int el = 0; el < 8; ++el) {
        const float4 k0 = *reinterpret_cast<const float4*>(&Ks[0][el][4 * u]);
        const float4 k1 =
            *reinterpret_cast<const float4*>(&Ks[0][el][256 + 4 * u]);
#pragma unroll
        for (int r = 0; r < 4; ++r) {
          const float q = qv[el][r];
          acc[r][0] = fmaf(q, k0.x, acc[r][0]);
          acc[r][1] = fmaf(q, k0.y, acc[r][1]);
          acc[r][2] = fmaf(q, k0.z, acc[r][2]);
          acc[r][3] = fmaf(q, k0.w, acc[r][3]);
          acc[r][4] = fmaf(q, k1.x, acc[r][4]);
          acc[r][5] = fmaf(q, k1.y, acc[r][5]);
          acc[r][6] = fmaf(q, k1.z, acc[r][6]);
          acc[r][7] = fmaf(q, k1.w, acc[r][7]);
        }
      }
      __syncthreads();
    }
    {  // ch = 1
      if (eo < 7) stage(0, eo + 1, 0);
#pragma unroll
      for (int el = 0; el < 8; ++el) {
        const float4 k0 = *reinterpret_cast<const float4*>(&Ks[1][el][4 * u]);
        const float4 k1 =
            *reinterpret_cast<const float4*>(&Ks[1][el][256 + 4 * u]);
#pragma unroll
        for (int r = 0; r < 4; ++r) {
          const float q = qv[el][r];
          acc[r][8] = fmaf(q, k0.x, acc[r][8]);
          acc[r][9] = fmaf(q, k0.y, acc[r][9]);
          acc[r][10] = fmaf(q, k0.z, acc[r][10]);
          acc[r][11] = fmaf(q, k0.w, acc[r][11]);
          acc[r][12] = fmaf(q, k1.x, acc[r][12]);
          acc[r][13] = fmaf(q, k1.y, acc[r][13]);
          acc[r][14] = fmaf(q, k1.z, acc[r][14]);
          acc[r][15] = fmaf(q, k1.w, acc[r][15]);
        }
      }
      __syncthreads();
    }
  }

  // ---- top-8 thresholds, 4 rows interleaved, descending extraction ----
  float T[4], cnt8[4], rowmax[4];
#pragma unroll
  for (int r = 0; r < 4; ++r) {
    T[r] = INFINITY;
    cnt8[r] = 0.0f;
    rowmax[r] = 0.0f;
  }

  for (int it = 0; it < TOPK_; ++it) {
    float m[4];
#pragma unroll
    for (int r = 0; r < 4; ++r) {
      float lm = -INFINITY;
#pragma unroll
      for (int j = 0; j < 16; ++j) {
        const float v = acc[r][j];
        lm = fmaxf(lm, v < T[r] ? v : -INFINITY);
      }
      m[r] = lm;
    }
    unsigned mu[4];
#pragma unroll
    for (int r = 0; r < 4; ++r) mu[r] = enc_ord(m[r]);
#pragma unroll
    for (int r = 0; r < 4; ++r) mu[r] = dpp_umax64(mu[r]);
#pragma unroll
    for (int r = 0; r < 4; ++r) m[r] = dec_ord(mu[r]);

    float nn[4];
#pragma unroll
    for (int r = 0; r < 4; ++r) {
      float cl = 0.0f;
#pragma unroll
      for (int j = 0; j < 16; ++j) cl += (acc[r][j] == m[r]) ? 1.0f : 0.0f;
      nn[r] = cl;
    }
#pragma unroll
    for (int r = 0; r < 4; ++r) nn[r] = dpp_fsum64(nn[r]);

#pragma unroll
    for (int r = 0; r < 4; ++r) {
      if (it == 0) rowmax[r] = m[r];
      const bool upd = (cnt8[r] < 8.0f);
      T[r] = upd ? m[r] : T[r];
      cnt8[r] = upd ? cnt8[r] + nn[r] : cnt8[r];
    }
  }

  // ---- softmax + masked write + compact lists (per row) ----
#pragma unroll
  for (int r = 0; r < 4; ++r) {
    const float thresh = T[r];
    float e16[16];
    float zl = 0.0f;
#pragma unroll
    for (int j = 0; j < 16; ++j) {
      const bool kept = (acc[r][j] >= thresh);
      const float e = kept ? __expf((acc[r][j] - rowmax[r]) * 0.125f) : 0.0f;
      e16[j] = e;
      zl += e;
    }
    const float zsum = dpp_fsum64(zl);
    const float inv = 1.0f / zsum;

    const long long row = row0 + wv * 4 + r;
    float* a = A + (row << 10);
    int cnt = 0;
#pragma unroll
    for (int j = 0; j < 16; ++j) {
      const bool kept = (acc[r][j] >= thresh);
      const float w = e16[j] * inv;
      e16[j] = kept ? w : 0.0f;
      const unsigned long long mk = __ballot(kept);
      if (kept) {
        const int pos = cnt + __popcll(mk & ((1ull << u) - 1ull));
        if (pos < 16) {
          const int col = (j >> 2) * 256 + 4 * u + (j & 3);
          outIdx[row * 16 + pos] = col;
          outW[row * 16 + pos] = w;
        }
      }
      cnt += __popcll(mk);
    }
    if (u == 0) outCnt[row] = cnt < 16 ? cnt : 16;

#pragma unroll
    for (int blkc = 0; blkc < 4; ++blkc) {
      float4 o;
      o.x = e16[blkc * 4 + 0];
      o.y = e16[blkc * 4 + 1];
      o.z = e16[blkc * 4 + 2];
      o.w = e16[blkc * 4 + 3];
      *reinterpret_cast<float4*>(&a[blkc * 256 + 4 * u]) = o;
    }
  }
}

// ---------------------------------------------------------------------------
// Sparse A*v from compact lists. One wave per row (lane = e).
// ---------------------------------------------------------------------------
__global__ __launch_bounds__(256) void vagg_kernel(
    const int* __restrict__ idx, const float* __restrict__ w,
    const int* __restrict__ cnt, const float* __restrict__ Vp,
    float* __restrict__ Vagg) {
  const int wave = threadIdx.x >> 6;
  const int lane = threadIdx.x & 63;
  const long long row = (long long)blockIdx.x * 4 + wave;
  const int b = (int)(row >> 14);
  const int h = (int)((row >> 10) & 15);
  const int l = (int)(row & 1023);
  const int n = cnt[row];
  float acc = 0.0f;
  for (int i = 0; i < n; ++i) {
    const int sI = idx[row * 16 + i];
    const float ww = w[row * 16 + i];
    acc += ww * Vp[((long long)((b << 10) + sI) << 10) + (h << 6) + lane];
  }
  Vagg[((long long)((b << 10) + l) << 10) + (h << 6) + lane] = acc;
}

extern "C" void kernel_launch(void* const* d_in, const int* in_sizes, int n_in,
                              void* d_out, int out_size, void* d_ws,
                              size_t ws_size, hipStream_t stream) {
  const float* queries = (const float*)d_in[0];
  const float* keys = (const float*)d_in[1];
  const float* values = (const float*)d_in[2];
  const float* Wq = (const float*)d_in[3];
  const float* bq = (const float*)d_in[4];
  const float* Wk = (const float*)d_in[5];
  const float* bk = (const float*)d_in[6];
  const float* Wv = (const float*)d_in[7];
  const float* bv = (const float*)d_in[8];
  const float* Wo = (const float*)d_in[9];
  const float* bo = (const float*)d_in[10];

  float* out = (float*)d_out;                   // [B,L,D]
  float* Aout = out + (long long)B_ * L_ * D_;  // [B,H,L,S]

  char* ws = (char*)d_ws;
  const size_t MD = (size_t)B_ * L_ * D_ * sizeof(float);  // 33.55 MB
  const size_t NL = (size_t)B_ * H_ * L_;                   // 131072 rows
  float* Qf = (float*)ws;
  float* Kf = (float*)(ws + MD);
  float* Kt = (float*)(ws + 2 * MD);
  int* tIdx = (int*)(ws + 3 * MD);
  float* tW = (float*)(ws + 3 * MD + NL * 16 * 4);
  int* tCnt = (int*)(ws + 3 * MD + NL * 16 * 8);
  float* Vb = (float*)(ws + 3 * MD + NL * 16 * 8 + NL * 4);
  float* Vagg = Kt;  // Kt dead after score_topk_fused

  const dim3 blk(256);
  const int M = B_ * L_;  // 8192

  // Q = relu(queries @ Wq^T + bq)   [bit-exact chain]
  gemm_abt<1><<<dim3(16, M / 64), blk, 0, stream>>>(queries, Wq, bq, Qf, M, D_,
                                                    D_, D_, D_, D_);
  // K = keys @ Wk^T + bk            [bit-exact chain]
  gemm_abt<0><<<dim3(16, M / 64), blk, 0, stream>>>(keys, Wk, bk, Kf, M, D_,
                                                    D_, D_, D_, D_);
  // Kt[b,h,e,s] = Kf[b,s,h,e]
  transpose_k<<<dim3(16, B_ * H_), blk, 0, stream>>>(Kf, Kt);

  // fused scores + top-8 + softmax -> A + compact lists
  score_topk_fused<<<(int)(NL / 16), blk, 0, stream>>>(Qf, Kt, Aout, tIdx, tW,
                                                       tCnt);

  // V = relu(values @ Wv^T + bv)    [value-level -> bf16 MFMA]
  gemm_mfma<1><<<dim3(16, M / 64), blk, 0, stream>>>(values, Wv, bv, Vb, M, D_,
                                                     D_, D_, D_, D_);

  // Vagg[b,l,h,:] = sum_s A * v   (writes into Kt slot)
  vagg_kernel<<<(int)(NL / 4), blk, 0, stream>>>(tIdx, tW, tCnt, Vb, Vagg);

  // out = Vagg @ Wo^T + bo          [value-level -> bf16 MFMA]
  gemm_mfma<0><<<dim3(16, M / 64), blk, 0, stream>>>(Vagg, Wo, bo, out, M, D_,
                                                     D_, D_, D_, D_);
}